// Round 1
// baseline (126.494 us; speedup 1.0000x reference)
//
#include <hip/hip_runtime.h>

// Problem constants (from reference): left/right [B, C, H, W] fp32
// out [B, 2C, D, H, W] fp32
#define BB 4
#define CC 32
#define HH 64
#define WW 128
#define DD 48

// One thread writes one float4 of the output (W=128 -> 32 float4 per row).
// Total float4 elements: B * 2C * D * H * (W/4) = 4*64*48*64*32 = 25,165,824.
__global__ __launch_bounds__(256) void cost_vol_kernel(
    const float* __restrict__ left,
    const float* __restrict__ right,
    float* __restrict__ out)
{
    int i = blockIdx.x * blockDim.x + threadIdx.x;  // < 25,165,824 (fits int)

    // Decompose: i = ((((b*64 + c2)*48 + d)*64 + h)*32 + w4)
    int w4 = i & 31;        // W/4 = 32
    int t  = i >> 5;
    int h  = t & 63;        // H = 64
    t >>= 6;
    int d  = t % 48;        // D = 48 (magic-mul)
    t /= 48;
    int c2 = t & 63;        // 2C = 64
    int b  = t >> 6;

    int w0 = w4 << 2;       // base w of this float4

    float4 v;
    if (c2 < CC) {
        // left half: left[b,c,h,w] * (w >= d)
        const float* src = left + (((b * CC + c2) * HH + h) * WW);
        float4 lv = *reinterpret_cast<const float4*>(src + w0);
        v.x = (w0     >= d) ? lv.x : 0.0f;
        v.y = (w0 + 1 >= d) ? lv.y : 0.0f;
        v.z = (w0 + 2 >= d) ? lv.z : 0.0f;
        v.w = (w0 + 3 >= d) ? lv.w : 0.0f;
    } else {
        // right half: right[b,c,h,w-d] * (w >= d)
        const float* src = right + (((b * CC + (c2 - CC)) * HH + h) * WW);
        v.x = (w0     >= d) ? src[w0     - d] : 0.0f;
        v.y = (w0 + 1 >= d) ? src[w0 + 1 - d] : 0.0f;
        v.z = (w0 + 2 >= d) ? src[w0 + 2 - d] : 0.0f;
        v.w = (w0 + 3 >= d) ? src[w0 + 3 - d] : 0.0f;
    }

    *reinterpret_cast<float4*>(out + (size_t)i * 4) = v;
}

extern "C" void kernel_launch(void* const* d_in, const int* in_sizes, int n_in,
                              void* d_out, int out_size, void* d_ws, size_t ws_size,
                              hipStream_t stream) {
    const float* left  = (const float*)d_in[0];
    const float* right = (const float*)d_in[1];
    float* out = (float*)d_out;

    const int total4 = BB * (2 * CC) * DD * HH * (WW / 4);  // 25,165,824
    const int block = 256;
    const int grid = total4 / block;                         // 98,304
    cost_vol_kernel<<<grid, block, 0, stream>>>(left, right, out);
}

// Round 2
// 77.480 us; speedup vs baseline: 1.6326x; 1.6326x over previous
//
#include <hip/hip_runtime.h>

// left/right: [B=4, C=32, H=64, W=128] fp32 ; out: [B, 2C=64, D=48, H, W] fp32
#define BB 4
#define CC 32
#define HH 64
#define WW 128
#define DD 48

// Block = 256 threads = dgroup(4) x h_loc(2) x w4(32).
// Grid  = B * C * (H/2) = 4096 blocks; each block owns (b, c, h0..h0+1) and
// emits all 48 disparities for both the left and right halves (96 KB out).
// Right rows staged once in LDS with swizzle slot = i + (i>>2) so the
// stride-4-dword gather (lanes w4=0..31 read dwords 4k+const) hits all 32
// banks (gcd(5,32)=1) instead of an 8-way conflict.
__global__ __launch_bounds__(256) void cost_vol_kernel(
    const float* __restrict__ left,
    const float* __restrict__ right,
    float* __restrict__ out)
{
    __shared__ float lds_r[2][160];   // 128 dwords swizzled -> max slot 158

    const int bx = blockIdx.x;
    const int hp = bx & 31;           // H/2 = 32
    const int c  = (bx >> 5) & 31;    // C  = 32
    const int b  = bx >> 10;          // B  = 4
    const int h0 = hp << 1;

    const int t = threadIdx.x;

    // ---- stage: right rows -> swizzled LDS (each input dword fetched once) --
    {
        const int row = t >> 7;       // 0..1
        const int i   = t & 127;
        const float* rrow = right + (((b * CC + c) * HH) + h0 + row) * WW;
        lds_r[row][i + (i >> 2)] = rrow[i];
    }

    const int w4    = t & 31;
    const int h_loc = (t >> 5) & 1;
    const int dg    = t >> 6;         // 0..3
    const int w0    = w4 << 2;

    // left float4 lives in registers across all 48 d (L1 serves the 4x dup)
    const float* lrow = left + (((b * CC + c) * HH) + h0 + h_loc) * WW;
    const float4 lv = *reinterpret_cast<const float4*>(lrow + w0);

    __syncthreads();

    const float* rl = lds_r[h_loc];

    // out[b][c2][d][h][w]; wave (uniform dg, h_loc 0..1, w4 0..31) stores 1 KB contiguous
    const size_t baseL =
        ((((size_t)(b * 2 * CC + c) * DD + dg) * HH) + h0 + h_loc) * WW + w0;
    float* pL = out + baseL;
    float* pR = pL + (size_t)CC * DD * HH * WW;   // c2 = c + 32

    #pragma unroll
    for (int iter = 0; iter < 12; ++iter) {
        const int d = dg + (iter << 2);
        const int e = w0 - d;

        float4 vl, vr;
        {
            int i0 = e;     int x0 = i0 < 0 ? 0 : i0; float r0 = rl[x0 + (x0 >> 2)];
            int i1 = e + 1; int x1 = i1 < 0 ? 0 : i1; float r1 = rl[x1 + (x1 >> 2)];
            int i2 = e + 2; int x2 = i2 < 0 ? 0 : i2; float r2 = rl[x2 + (x2 >> 2)];
            int i3 = e + 3; int x3 = i3 < 0 ? 0 : i3; float r3 = rl[x3 + (x3 >> 2)];
            vl.x = (i0 >= 0) ? lv.x : 0.0f;  vr.x = (i0 >= 0) ? r0 : 0.0f;
            vl.y = (i1 >= 0) ? lv.y : 0.0f;  vr.y = (i1 >= 0) ? r1 : 0.0f;
            vl.z = (i2 >= 0) ? lv.z : 0.0f;  vr.z = (i2 >= 0) ? r2 : 0.0f;
            vl.w = (i3 >= 0) ? lv.w : 0.0f;  vr.w = (i3 >= 0) ? r3 : 0.0f;
        }
        *reinterpret_cast<float4*>(pL) = vl;
        *reinterpret_cast<float4*>(pR) = vr;

        pL += 4 * HH * WW;   // d += 4
        pR += 4 * HH * WW;
    }
}

extern "C" void kernel_launch(void* const* d_in, const int* in_sizes, int n_in,
                              void* d_out, int out_size, void* d_ws, size_t ws_size,
                              hipStream_t stream) {
    const float* left  = (const float*)d_in[0];
    const float* right = (const float*)d_in[1];
    float* out = (float*)d_out;

    const int grid  = BB * CC * (HH / 2);   // 4096
    const int block = 256;
    cost_vol_kernel<<<grid, block, 0, stream>>>(left, right, out);
}